// Round 8
// baseline (312.899 us; speedup 1.0000x reference)
//
#include <hip/hip_runtime.h>

typedef unsigned short u16;
typedef unsigned int u32;
typedef __attribute__((ext_vector_type(2))) u32 u32x2;
typedef __attribute__((ext_vector_type(4))) u32 u32x4;
typedef __attribute__((ext_vector_type(4))) float f32x4;
typedef __attribute__((ext_vector_type(8))) short s16x8;

#define DEV __device__ __forceinline__

DEV float bflo(u32 u){ union{u32 i; float f;} c; c.i = u << 16; return c.f; }
DEV float bfhi(u32 u){ union{u32 i; float f;} c; c.i = u & 0xffff0000u; return c.f; }
DEV float b2f(u16 v){ union{u32 i; float f;} c; c.i = ((u32)v) << 16; return c.f; }
DEV u16 f2b(float f){
  union{float f; u32 u;} c; c.f = f;
  u32 u = c.u;
  u32 r = (u + 0x7fffu + ((u >> 16) & 1u)) >> 16;
  return (u16)r;
}
DEV float fsilu(float v){ return v / (1.f + __expf(-v)); }

// async global->LDS, 16B per lane; lds dst must be wave-uniform base
#define GLD_LDS16(gsrc, ldst)                                                  \
  __builtin_amdgcn_global_load_lds(                                            \
      (const __attribute__((address_space(1))) u32*)(gsrc),                    \
      (__attribute__((address_space(3))) u32*)(ldst), 16, 0, 0)

constexpr int Bn = 32, Cin = 64, H = 56, Wd = 56, HID = 384, CO = 64;
constexpr int HW = H * Wd;            // 3136
constexpr float EPS = 1e-5f;

constexpr int XROW = 72 * 64;         // xt: [58 yrow][72 slot][64 ic] bf16
constexpr int XBATCH = 58 * XROW;
// wt: [octile 3][tap 9][kk 2][ocl 128][quad 4][8] bf16 (A-frag linear order)
constexpr int WKK = 128 * 32;         // 4096 elems per (tap,kk)
constexpr int WOCT = 9 * 2 * WKK;     // 73728 per octile

// ---------------------------------------------------------------------------
// P1: pack expand weights -> wt, A-fragment-linear (coalesced wave loads).
// ---------------------------------------------------------------------------
__global__ __launch_bounds__(256) void k_prep_w(
    const float* __restrict__ w, u16* __restrict__ wt)
{
  int t = blockIdx.x * 256 + threadIdx.x;        // < 3*73728 = 221184
  int j = t & 7, quad = (t >> 3) & 3, ocl = (t >> 5) & 127;
  int kk = (t >> 12) & 1, rest = t >> 13;        // rest = octile*9 + tap
  int tap = rest % 9, octile = rest / 9;
  int ic = kk * 32 + quad * 8 + j;
  int oc = octile * 128 + ocl;
  wt[t] = f2b(w[(oc * Cin + ic) * 9 + tap]);
}

// ---------------------------------------------------------------------------
// P2: BN1 + BN3 scale/shift arrays.
// ---------------------------------------------------------------------------
__global__ __launch_bounds__(384) void k_prep_bn(
    const float* __restrict__ g1, const float* __restrict__ b1,
    const float* __restrict__ m1, const float* __restrict__ v1,
    const float* __restrict__ g3, const float* __restrict__ b3,
    const float* __restrict__ m3, const float* __restrict__ v3,
    float* __restrict__ sc1, float* __restrict__ sh1,
    float* __restrict__ sc3, float* __restrict__ sh3)
{
  int t = threadIdx.x;
  if (t < HID) {
    float sc = g1[t] * rsqrtf(v1[t] + EPS);
    sc1[t] = sc;
    sh1[t] = b1[t] - m1[t] * sc;
  }
  if (t < CO) {
    float sc = g3[t] * rsqrtf(v3[t] + EPS);
    sc3[t] = sc;
    sh3[t] = b3[t] - m3[t] * sc;
  }
}

// ---------------------------------------------------------------------------
// P3: NCHW f32 -> padded NHWC bf16 (swizzled) xt. grid (58 yrow, bc b).
// ---------------------------------------------------------------------------
__global__ __launch_bounds__(256) void k_prep_x(
    const float* __restrict__ x, u16* __restrict__ xt, int b0)
{
  __shared__ u16 sT[56 * 68];
  const int yrow = blockIdx.x, b = blockIdx.y;
  const int gb = b0 + b;
  const int tid = threadIdx.x;
  u16* dst = xt + (size_t)b * XBATCH + (size_t)yrow * XROW;

  if (yrow == 0 || yrow == 57) {
    u32x4 z = {0, 0, 0, 0};
    for (int i = tid; i < 576; i += 256) *(u32x4*)&dst[i * 8] = z;
    return;
  }
  const int y = yrow - 1;
  #pragma unroll
  for (int pass = 0; pass < 16; ++pass) {
    int ic = pass * 4 + (tid >> 6), xx = tid & 63;
    if (xx < 56)
      sT[xx * 68 + ic] = f2b(x[((size_t)(gb * Cin + ic) * H + y) * Wd + xx]);
  }
  __syncthreads();
  for (int t = tid; t < 576; t += 256) {
    int slot = t >> 3, physo = t & 7;
    u32x4 v = {0, 0, 0, 0};
    if (slot >= 1 && slot <= 56) {
      int olog = physo ^ (slot & 7);
      const u32* sp = (const u32*)&sT[(slot - 1) * 68 + olog * 8];
      v.x = sp[0]; v.y = sp[1]; v.z = sp[2]; v.w = sp[3];
    }
    *(u32x4*)&dst[t * 8] = v;
  }
}

// ---------------------------------------------------------------------------
// K1: expand conv MFMA shift-GEMM. A-frags straight from global (L2-hot wt);
// LDS holds only sB -> 4 blocks/CU; NO barrier in the main loop.
// grid (3 octile, 28 ypair, bc b), 256 thr.
// ---------------------------------------------------------------------------
__global__ __launch_bounds__(256, 4) void k_expand_mfma(
    const u16* __restrict__ xt, const u16* __restrict__ wt,
    const float* __restrict__ sc1, const float* __restrict__ sh1,
    u16* __restrict__ h)
{
  __shared__ u16 sB[4 * XROW];      // 36,864 B
  const int tid = threadIdx.x;
  const int octile = blockIdx.x, ypair = blockIdx.y, b = blockIdx.z;
  const int y0 = ypair * 2;
  const int wave = tid >> 6, ln = tid & 63;
  const int wm = wave >> 1, wn = wave & 1;
  const int lane15 = ln & 15, quad = ln >> 4;

  // stage sB (36 KB linear) via async DMA, once
  {
    const u16* src = xt + (size_t)b * XBATCH + (size_t)y0 * XROW;
    #pragma unroll
    for (int it = 0; it < 9; ++it) {
      int off = (wave * 9 + it) * 512;            // 1 KB chunks
      GLD_LDS16(src + off + ln * 8, &sB[off]);
    }
  }
  __syncthreads();   // sB ready; no further barriers

  f32x4 acc[4][4];
  #pragma unroll
  for (int ms = 0; ms < 4; ++ms)
    #pragma unroll
    for (int ns = 0; ns < 4; ++ns) acc[ms][ns] = (f32x4){0.f, 0.f, 0.f, 0.f};

  const u16* wbase = wt + (size_t)octile * WOCT;
  const int laneA = (wm * 64 + lane15) * 32 + quad * 8;

  #pragma unroll
  for (int tap = 0; tap < 9; ++tap) {
    const int dy = tap / 3, dx = tap - dy * 3;
    #pragma unroll
    for (int kk = 0; kk < 2; ++kk) {
      const u16* wp = wbase + (tap * 2 + kk) * WKK + laneA;
      s16x8 af[4], bf[4];
      #pragma unroll
      for (int ms = 0; ms < 4; ++ms)
        af[ms] = *(const s16x8*)(wp + ms * 512);   // 16 ocl x 32 = 512
      #pragma unroll
      for (int ns = 0; ns < 4; ++ns) {
        int row = wn + dy;
        int slot = ns * 16 + lane15 + dx;
        int po = (kk * 4 + quad) ^ (slot & 7);
        bf[ns] = *(const s16x8*)&sB[(row * 72 + slot) * 64 + po * 8];
      }
      #pragma unroll
      for (int ms = 0; ms < 4; ++ms)
        #pragma unroll
        for (int ns = 0; ns < 4; ++ns)
          acc[ms][ns] = __builtin_amdgcn_mfma_f32_16x16x32_bf16(
              af[ms], bf[ns], acc[ms][ns], 0, 0, 0);
    }
  }

  const int y = y0 + wn;
  #pragma unroll
  for (int ms = 0; ms < 4; ++ms) {
    int oc0 = octile * 128 + wm * 64 + ms * 16 + quad * 4;
    f32x4 sc = *(const f32x4*)&sc1[oc0];
    f32x4 sh = *(const f32x4*)&sh1[oc0];
    float scr[4] = {sc.x, sc.y, sc.z, sc.w};
    float shr[4] = {sh.x, sh.y, sh.z, sh.w};
    #pragma unroll
    for (int ns = 0; ns < 4; ++ns) {
      int xg = ns * 16 + lane15;
      if (xg < Wd) {
        float av[4] = {acc[ms][ns].x, acc[ms][ns].y, acc[ms][ns].z, acc[ms][ns].w};
        #pragma unroll
        for (int r = 0; r < 4; ++r) {
          float val = fsilu(av[r] * scr[r] + shr[r]);
          h[((size_t)(b * HID + oc0 + r) * H + y) * Wd + xg] = f2b(val);
        }
      }
    }
  }
}

// ---------------------------------------------------------------------------
// K2: depthwise 3x3 + BN2 + SiLU -> d (bf16) + per-(b,c) mean.
// ---------------------------------------------------------------------------
__global__ __launch_bounds__(256) void k_dw(
    const u16* __restrict__ h, const float* __restrict__ wdw,
    const float* __restrict__ g2, const float* __restrict__ b2,
    const float* __restrict__ m2, const float* __restrict__ v2,
    u16* __restrict__ d, float* __restrict__ mean)
{
  __shared__ float sp[58 * 60];
  __shared__ float red[4];
  const int tid = threadIdx.x;
  const int c = blockIdx.x, b = blockIdx.y;
  const u16* hp = h + (size_t)(b * HID + c) * HW;

  if (tid < 228) {
    int r, cc;
    if (tid < 58)       { r = 0;              cc = tid; }
    else if (tid < 116) { r = 57;             cc = tid - 58; }
    else if (tid < 172) { r = tid - 116 + 1;  cc = 0; }
    else                { r = tid - 172 + 1;  cc = 57; }
    sp[r * 60 + cc] = 0.f;
  }
  for (int t = tid; t < 56 * 7; t += 256) {
    int r = t / 7, ch = t - r * 7;
    u32x4 q = *(const u32x4*)(hp + r * Wd + ch * 8);
    float* dst = &sp[(r + 1) * 60 + 1 + ch * 8];
    u32 ua[4] = {q.x, q.y, q.z, q.w};
    #pragma unroll
    for (int j = 0; j < 4; ++j) {
      dst[2 * j]     = bflo(ua[j]);
      dst[2 * j + 1] = bfhi(ua[j]);
    }
  }
  float wv[9];
  #pragma unroll
  for (int t = 0; t < 9; ++t) wv[t] = wdw[c * 9 + t];
  float sc = g2[c] * rsqrtf(v2[c] + EPS);
  float sh = b2[c] - m2[c] * sc;
  __syncthreads();

  u16* dp = d + (size_t)(b * HID + c) * HW;
  float lsum = 0.f;
  for (int g = tid; g < 784; g += 256) {
    int row = g / 14, gx = (g - row * 14) * 4;
    float v[3][6];
    #pragma unroll
    for (int r = 0; r < 3; ++r) {
      const float* pr = &sp[(row + r) * 60 + gx];
      f32x4 a = *(const f32x4*)pr;
      v[r][0] = a.x; v[r][1] = a.y; v[r][2] = a.z; v[r][3] = a.w;
      v[r][4] = pr[4]; v[r][5] = pr[5];
    }
    float o[4];
    #pragma unroll
    for (int j = 0; j < 4; ++j) {
      float s = 0.f;
      #pragma unroll
      for (int r = 0; r < 3; ++r)
        #pragma unroll
        for (int dx = 0; dx < 3; ++dx)
          s += v[r][j + dx] * wv[r * 3 + dx];
      o[j] = fsilu(s * sc + sh);
      lsum += o[j];
    }
    u32x2 pk;
    pk.x = (u32)f2b(o[0]) | ((u32)f2b(o[1]) << 16);
    pk.y = (u32)f2b(o[2]) | ((u32)f2b(o[3]) << 16);
    *(u32x2*)&dp[row * 56 + gx] = pk;
  }
  #pragma unroll
  for (int off = 32; off > 0; off >>= 1) lsum += __shfl_down(lsum, off);
  if ((tid & 63) == 0) red[tid >> 6] = lsum;
  __syncthreads();
  if (tid == 0)
    mean[b * HID + c] = (red[0] + red[1] + red[2] + red[3]) * (1.f / 3136.f);
}

// ---------------------------------------------------------------------------
// K3: SE + A'-fold fused. grid bc, block 256.
// sfac kept in LDS; afold = wpw * sfac * sc3 (bf16).
// ---------------------------------------------------------------------------
__global__ __launch_bounds__(256) void k_se_a(
    const float* __restrict__ mean, const float* __restrict__ w1,
    const float* __restrict__ w2, const float* __restrict__ wpw,
    const float* __restrict__ sc3, u16* __restrict__ afold)
{
  __shared__ float sm[HID];
  __shared__ float ps[16 * 17];
  __shared__ float s1[16];
  __shared__ float sf[HID];
  const int b = blockIdx.x, tid = threadIdx.x;
  for (int c = tid; c < HID; c += 256) sm[c] = mean[b * HID + c];
  __syncthreads();
  int r = tid >> 4, j = tid & 15;
  float p = 0.f;
  for (int c = j; c < HID; c += 16) p += sm[c] * w1[r * HID + c];
  ps[r * 17 + j] = p;
  __syncthreads();
  if (tid < 16) {
    float s = 0.f;
    #pragma unroll
    for (int q = 0; q < 16; ++q) s += ps[tid * 17 + q];
    s1[tid] = fsilu(s);
  }
  __syncthreads();
  for (int c = tid; c < HID; c += 256) {
    float s = 0.f;
    #pragma unroll
    for (int q = 0; q < 16; ++q) s += s1[q] * w2[c * 16 + q];
    sf[c] = 1.f / (1.f + __expf(-s));
  }
  __syncthreads();
  for (int i = tid; i < 6144; i += 256) {    // f32x4 chunks of 64x384
    int e = i * 4, co = e / 384, k = e - co * 384;
    f32x4 wv = *(const f32x4*)&wpw[e];
    float s3 = sc3[co];
    u32x2 pk;
    pk.x = (u32)f2b(wv.x * sf[k] * s3)     | ((u32)f2b(wv.y * sf[k+1] * s3) << 16);
    pk.y = (u32)f2b(wv.z * sf[k+2] * s3)   | ((u32)f2b(wv.w * sf[k+3] * s3) << 16);
    *(u32x2*)&afold[(size_t)b * 24576 + e] = pk;
  }
}

// ---------------------------------------------------------------------------
// K4: pointwise MFMA GEMM. grid (25 px-tiles of 128, bc b), 256 thr.
// ---------------------------------------------------------------------------
constexpr int PWP = 392;

__global__ __launch_bounds__(256, 2) void k_pw_mfma(
    const u16* __restrict__ d, const u16* __restrict__ afold,
    const float* __restrict__ sh3,
    const float* __restrict__ x, float* __restrict__ out, int b0)
{
  __shared__ u16 sAw[64 * PWP];     // 50,176 B
  __shared__ u32 dt32[128 * 16];    // 8,192 B
  const int tid = threadIdx.x;
  const int b = blockIdx.y, gb = b0 + b;
  const int p0 = blockIdx.x * 128;
  const int wave = tid >> 6, ln = tid & 63;
  const int lane15 = ln & 15, quad = ln >> 4;

  // stage A' (pure b128 copies): 24576 elems = 3072 x 8
  {
    const u16* ab = afold + (size_t)b * 24576;
    #pragma unroll
    for (int i = tid; i < 3072; i += 256) {
      int e = i * 8, co = e / 384, k = e - co * 384;
      *(u32x4*)&sAw[co * PWP + k] = *(const u32x4*)&ab[e];
    }
  }

  f32x4 acc[4][2];
  #pragma unroll
  for (int ms = 0; ms < 4; ++ms)
    #pragma unroll
    for (int ns = 0; ns < 2; ++ns) acc[ms][ns] = (f32x4){0.f, 0.f, 0.f, 0.f};

  const int cpair = tid >> 4;
  const int pxo = (tid & 15) * 8;

  for (int ks = 0; ks < 12; ++ks) {
    const int k0 = ks * 32;
    __syncthreads();
    {
      u32x4 r0 = {0,0,0,0}, r1 = {0,0,0,0};
      if (p0 + pxo + 8 <= HW) {
        int c = k0 + 2 * cpair;
        const u16* dpp = d + (size_t)(b * HID + c) * HW + p0 + pxo;
        r0 = *(const u32x4*)dpp;
        r1 = *(const u32x4*)(dpp + HW);
      }
      u32* w0 = &dt32[pxo * 16 + cpair];
      w0[0 * 16] = (r0.x & 0xffffu) | (r1.x << 16);
      w0[1 * 16] = (r0.x >> 16)     | (r1.x & 0xffff0000u);
      w0[2 * 16] = (r0.y & 0xffffu) | (r1.y << 16);
      w0[3 * 16] = (r0.y >> 16)     | (r1.y & 0xffff0000u);
      w0[4 * 16] = (r0.z & 0xffffu) | (r1.z << 16);
      w0[5 * 16] = (r0.z >> 16)     | (r1.z & 0xffff0000u);
      w0[6 * 16] = (r0.w & 0xffffu) | (r1.w << 16);
      w0[7 * 16] = (r0.w >> 16)     | (r1.w & 0xffff0000u);
    }
    __syncthreads();
    s16x8 af[4], bf[2];
    #pragma unroll
    for (int ms = 0; ms < 4; ++ms) {
      int ocl = ms * 16 + lane15;
      af[ms] = *(const s16x8*)&sAw[ocl * PWP + k0 + quad * 8];
    }
    #pragma unroll
    for (int ns = 0; ns < 2; ++ns) {
      int px = wave * 32 + ns * 16 + lane15;
      bf[ns] = *(const s16x8*)((const u16*)dt32 + px * 32 + quad * 8);
    }
    #pragma unroll
    for (int ms = 0; ms < 4; ++ms)
      #pragma unroll
      for (int ns = 0; ns < 2; ++ns)
        acc[ms][ns] = __builtin_amdgcn_mfma_f32_16x16x32_bf16(
            af[ms], bf[ns], acc[ms][ns], 0, 0, 0);
  }

  #pragma unroll
  for (int ns = 0; ns < 2; ++ns) {
    int p = p0 + wave * 32 + ns * 16 + lane15;
    if (p < HW) {
      #pragma unroll
      for (int ms = 0; ms < 4; ++ms) {
        int co0 = ms * 16 + quad * 4;
        float av[4] = {acc[ms][ns].x, acc[ms][ns].y, acc[ms][ns].z, acc[ms][ns].w};
        #pragma unroll
        for (int r = 0; r < 4; ++r) {
          size_t idx = (size_t)(gb * CO + co0 + r) * HW + p;
          out[idx] = av[r] + sh3[co0 + r] + x[idx];
        }
      }
    }
  }
}

// ---------------------------------------------------------------------------
extern "C" void kernel_launch(void* const* d_in, const int* in_sizes, int n_in,
                              void* d_out, int out_size, void* d_ws, size_t ws_size,
                              hipStream_t stream)
{
  (void)in_sizes; (void)n_in; (void)out_size;
  const float* x     = (const float*)d_in[0];
  const float* w_exp = (const float*)d_in[1];
  const float* g1 = (const float*)d_in[2];
  const float* b1 = (const float*)d_in[3];
  const float* m1 = (const float*)d_in[4];
  const float* v1 = (const float*)d_in[5];
  const float* w_dw = (const float*)d_in[6];
  const float* g2 = (const float*)d_in[7];
  const float* b2 = (const float*)d_in[8];
  const float* m2 = (const float*)d_in[9];
  const float* v2 = (const float*)d_in[10];
  const float* w_se1 = (const float*)d_in[11];
  const float* w_se2 = (const float*)d_in[12];
  const float* w_pw  = (const float*)d_in[13];
  const float* g3 = (const float*)d_in[14];
  const float* b3 = (const float*)d_in[15];
  const float* m3 = (const float*)d_in[16];
  const float* v3 = (const float*)d_in[17];

  const size_t perB = (size_t)XBATCH * 2 + (size_t)HID * HW * 2 * 2
                    + 24576 * 2 + HID * 4;
  const size_t fixed = 221184 * 2 + HID * 8 + CO * 8;
  int bc = Bn;
  while (bc > 1 && fixed + (size_t)bc * perB > ws_size) bc >>= 1;

  u16* wt = (u16*)d_ws;
  float* sc1 = (float*)(wt + 221184);
  float* sh1 = sc1 + HID;
  float* sc3 = sh1 + HID;
  float* sh3 = sc3 + CO;
  u16* xt = (u16*)(sh3 + CO);
  u16* h  = xt + (size_t)bc * XBATCH;
  u16* dd = h + (size_t)bc * HID * HW;
  u16* afold = dd + (size_t)bc * HID * HW;
  float* mean = (float*)(afold + (size_t)bc * 24576);

  k_prep_w<<<864, 256, 0, stream>>>(w_exp, wt);
  k_prep_bn<<<1, 384, 0, stream>>>(g1, b1, m1, v1, g3, b3, m3, v3,
                                   sc1, sh1, sc3, sh3);

  for (int b0 = 0; b0 < Bn; b0 += bc) {
    k_prep_x<<<dim3(58, bc), 256, 0, stream>>>(x, xt, b0);
    k_expand_mfma<<<dim3(3, 28, bc), 256, 0, stream>>>(xt, wt, sc1, sh1, h);
    k_dw<<<dim3(HID, bc), 256, 0, stream>>>(h, w_dw, g2, b2, m2, v2, dd, mean);
    k_se_a<<<bc, 256, 0, stream>>>(mean, w_se1, w_se2, w_pw, sc3, afold);
    k_pw_mfma<<<dim3(25, bc), 256, 0, stream>>>(dd, afold, sh3,
                                                x, (float*)d_out, b0);
  }
}

// Round 9
// 312.840 us; speedup vs baseline: 1.0002x; 1.0002x over previous
//
#include <hip/hip_runtime.h>

typedef unsigned short u16;
typedef unsigned int u32;
typedef __attribute__((ext_vector_type(2))) u32 u32x2;
typedef __attribute__((ext_vector_type(4))) u32 u32x4;
typedef __attribute__((ext_vector_type(4))) float f32x4;
typedef __attribute__((ext_vector_type(8))) short s16x8;

#define DEV __device__ __forceinline__

DEV float bflo(u32 u){ union{u32 i; float f;} c; c.i = u << 16; return c.f; }
DEV float bfhi(u32 u){ union{u32 i; float f;} c; c.i = u & 0xffff0000u; return c.f; }
DEV float b2f(u16 v){ union{u32 i; float f;} c; c.i = ((u32)v) << 16; return c.f; }
DEV u16 f2b(float f){
  union{float f; u32 u;} c; c.f = f;
  u32 u = c.u;
  u32 r = (u + 0x7fffu + ((u >> 16) & 1u)) >> 16;
  return (u16)r;
}
DEV float fsilu(float v){ return v / (1.f + __expf(-v)); }

// async global->LDS, 16B per lane; lds dst must be wave-uniform base
#define GLD_LDS16(gsrc, ldst)                                                  \
  __builtin_amdgcn_global_load_lds(                                            \
      (const __attribute__((address_space(1))) u32*)(gsrc),                    \
      (__attribute__((address_space(3))) u32*)(ldst), 16, 0, 0)

constexpr int Bn = 32, Cin = 64, H = 56, Wd = 56, HID = 384, CO = 64;
constexpr int HW = H * Wd;            // 3136
constexpr float EPS = 1e-5f;

constexpr int XROW = 72 * 64;         // xt: [58 yrow][72 slot][64 ic] bf16
constexpr int XBATCH = 58 * XROW;
// wt: [octile 3][tap 9][kk 2][ocl 128][quad 4][8] bf16 (A-frag linear order)
constexpr int WKK = 128 * 32;         // 4096 elems per (tap,kk)
constexpr int WOCT = 9 * 2 * WKK;     // 73728 per octile

// ---------------------------------------------------------------------------
// P1: pack expand weights -> wt, A-fragment-linear (coalesced wave loads).
// ---------------------------------------------------------------------------
__global__ __launch_bounds__(256) void k_prep_w(
    const float* __restrict__ w, u16* __restrict__ wt)
{
  int t = blockIdx.x * 256 + threadIdx.x;        // < 3*73728 = 221184
  int j = t & 7, quad = (t >> 3) & 3, ocl = (t >> 5) & 127;
  int kk = (t >> 12) & 1, rest = t >> 13;        // rest = octile*9 + tap
  int tap = rest % 9, octile = rest / 9;
  int ic = kk * 32 + quad * 8 + j;
  int oc = octile * 128 + ocl;
  wt[t] = f2b(w[(oc * Cin + ic) * 9 + tap]);
}

// ---------------------------------------------------------------------------
// P2: BN1 + BN3 scale/shift arrays.
// ---------------------------------------------------------------------------
__global__ __launch_bounds__(384) void k_prep_bn(
    const float* __restrict__ g1, const float* __restrict__ b1,
    const float* __restrict__ m1, const float* __restrict__ v1,
    const float* __restrict__ g3, const float* __restrict__ b3,
    const float* __restrict__ m3, const float* __restrict__ v3,
    float* __restrict__ sc1, float* __restrict__ sh1,
    float* __restrict__ sc3, float* __restrict__ sh3)
{
  int t = threadIdx.x;
  if (t < HID) {
    float sc = g1[t] * rsqrtf(v1[t] + EPS);
    sc1[t] = sc;
    sh1[t] = b1[t] - m1[t] * sc;
  }
  if (t < CO) {
    float sc = g3[t] * rsqrtf(v3[t] + EPS);
    sc3[t] = sc;
    sh3[t] = b3[t] - m3[t] * sc;
  }
}

// ---------------------------------------------------------------------------
// P3: NCHW f32 -> padded NHWC bf16 (swizzled) xt. grid (58 yrow, bc b).
// ---------------------------------------------------------------------------
__global__ __launch_bounds__(256) void k_prep_x(
    const float* __restrict__ x, u16* __restrict__ xt, int b0)
{
  __shared__ u16 sT[56 * 68];
  const int yrow = blockIdx.x, b = blockIdx.y;
  const int gb = b0 + b;
  const int tid = threadIdx.x;
  u16* dst = xt + (size_t)b * XBATCH + (size_t)yrow * XROW;

  if (yrow == 0 || yrow == 57) {
    u32x4 z = {0, 0, 0, 0};
    for (int i = tid; i < 576; i += 256) *(u32x4*)&dst[i * 8] = z;
    return;
  }
  const int y = yrow - 1;
  #pragma unroll
  for (int pass = 0; pass < 16; ++pass) {
    int ic = pass * 4 + (tid >> 6), xx = tid & 63;
    if (xx < 56)
      sT[xx * 68 + ic] = f2b(x[((size_t)(gb * Cin + ic) * H + y) * Wd + xx]);
  }
  __syncthreads();
  for (int t = tid; t < 576; t += 256) {
    int slot = t >> 3, physo = t & 7;
    u32x4 v = {0, 0, 0, 0};
    if (slot >= 1 && slot <= 56) {
      int olog = physo ^ (slot & 7);
      const u32* sp = (const u32*)&sT[(slot - 1) * 68 + olog * 8];
      v.x = sp[0]; v.y = sp[1]; v.z = sp[2]; v.w = sp[3];
    }
    *(u32x4*)&dst[t * 8] = v;
  }
}

// ---------------------------------------------------------------------------
// K1: expand conv MFMA shift-GEMM v3.
// Block = 128 oc x 4 output rows (256 px). grid (3 octile, 14 yquad, bc).
// Wave (wm,wp) = 64 oc x 2 rows. 32 MFMA per (tap,kk) iteration.
// A-fragments register-double-buffered from global (L2-hot wt).
// LDS: sB only (6 input rows, 55.3 KB) -> 2 blocks/CU. No loop barriers.
// ---------------------------------------------------------------------------
__global__ __launch_bounds__(256, 2) void k_expand_mfma(
    const u16* __restrict__ xt, const u16* __restrict__ wt,
    const float* __restrict__ sc1, const float* __restrict__ sh1,
    u16* __restrict__ h)
{
  __shared__ u16 sB[6 * XROW];      // 55,296 B
  const int tid = threadIdx.x;
  const int octile = blockIdx.x, yq = blockIdx.y, b = blockIdx.z;
  const int y0 = yq * 4;
  const int wave = tid >> 6, ln = tid & 63;
  const int wm = wave >> 1, wp = wave & 1;
  const int lane15 = ln & 15, quad = ln >> 4;

  // stage sB: 6 yrows (y0 .. y0+5 physical, logical y0-1..y0+4), 27648 elems
  {
    const u16* src = xt + (size_t)b * XBATCH + (size_t)y0 * XROW;
    #pragma unroll
    for (int it = 0; it < 13; ++it) {
      int off = it * 2048 + wave * 512;
      GLD_LDS16(src + off + ln * 8, &sB[off]);
    }
    if (wave < 2) {
      int off = 26624 + wave * 512;
      GLD_LDS16(src + off + ln * 8, &sB[off]);
    }
  }
  __syncthreads();   // sB ready; no further barriers

  f32x4 acc[4][8];   // [ms][r*4+ns]
  #pragma unroll
  for (int ms = 0; ms < 4; ++ms)
    #pragma unroll
    for (int nn = 0; nn < 8; ++nn) acc[ms][nn] = (f32x4){0.f, 0.f, 0.f, 0.f};

  const u16* wbase = wt + (size_t)octile * WOCT;
  const int laneA = (wm * 64 + lane15) * 32 + quad * 8;

  // preload A for iteration 0
  s16x8 afc[4], afn[4];
  #pragma unroll
  for (int ms = 0; ms < 4; ++ms)
    afc[ms] = *(const s16x8*)(wbase + laneA + ms * 512);

  #pragma unroll
  for (int it = 0; it < 18; ++it) {
    const int tap = it >> 1, kk = it & 1;
    const int dy = tap / 3, dx = tap - dy * 3;
    // register prefetch of next iteration's A (hidden under 32 MFMAs)
    if (it < 17) {
      const u16* wp_ = wbase + (it + 1) * WKK + laneA;
      #pragma unroll
      for (int ms = 0; ms < 4; ++ms)
        afn[ms] = *(const s16x8*)(wp_ + ms * 512);
    }
    #pragma unroll
    for (int r = 0; r < 2; ++r) {
      const int row = 2 * wp + r + dy;
      s16x8 bf[4];
      #pragma unroll
      for (int ns = 0; ns < 4; ++ns) {
        int slot = ns * 16 + lane15 + dx;
        int po = (kk * 4 + quad) ^ ((lane15 + dx) & 7);
        bf[ns] = *(const s16x8*)&sB[(row * 72 + slot) * 64 + po * 8];
      }
      #pragma unroll
      for (int ms = 0; ms < 4; ++ms)
        #pragma unroll
        for (int ns = 0; ns < 4; ++ns)
          acc[ms][r * 4 + ns] = __builtin_amdgcn_mfma_f32_16x16x32_bf16(
              afc[ms], bf[ns], acc[ms][r * 4 + ns], 0, 0, 0);
    }
    #pragma unroll
    for (int ms = 0; ms < 4; ++ms) afc[ms] = afn[ms];
  }

  // epilogue: BN1 + SiLU, store h bf16 for 2 rows
  #pragma unroll
  for (int ms = 0; ms < 4; ++ms) {
    int oc0 = octile * 128 + wm * 64 + ms * 16 + quad * 4;
    f32x4 sc = *(const f32x4*)&sc1[oc0];
    f32x4 sh = *(const f32x4*)&sh1[oc0];
    float scr[4] = {sc.x, sc.y, sc.z, sc.w};
    float shr[4] = {sh.x, sh.y, sh.z, sh.w};
    #pragma unroll
    for (int r = 0; r < 2; ++r) {
      const int y = y0 + 2 * wp + r;
      #pragma unroll
      for (int ns = 0; ns < 4; ++ns) {
        int xg = ns * 16 + lane15;
        if (xg < Wd) {
          f32x4 a = acc[ms][r * 4 + ns];
          float av[4] = {a.x, a.y, a.z, a.w};
          #pragma unroll
          for (int q = 0; q < 4; ++q) {
            float val = fsilu(av[q] * scr[q] + shr[q]);
            h[((size_t)(b * HID + oc0 + q) * H + y) * Wd + xg] = f2b(val);
          }
        }
      }
    }
  }
}

// ---------------------------------------------------------------------------
// K2: depthwise 3x3 + BN2 + SiLU -> d (bf16) + per-(b,c) mean.
// ---------------------------------------------------------------------------
__global__ __launch_bounds__(256) void k_dw(
    const u16* __restrict__ h, const float* __restrict__ wdw,
    const float* __restrict__ g2, const float* __restrict__ b2,
    const float* __restrict__ m2, const float* __restrict__ v2,
    u16* __restrict__ d, float* __restrict__ mean)
{
  __shared__ float sp[58 * 60];
  __shared__ float red[4];
  const int tid = threadIdx.x;
  const int c = blockIdx.x, b = blockIdx.y;
  const u16* hp = h + (size_t)(b * HID + c) * HW;

  if (tid < 228) {
    int r, cc;
    if (tid < 58)       { r = 0;              cc = tid; }
    else if (tid < 116) { r = 57;             cc = tid - 58; }
    else if (tid < 172) { r = tid - 116 + 1;  cc = 0; }
    else                { r = tid - 172 + 1;  cc = 57; }
    sp[r * 60 + cc] = 0.f;
  }
  for (int t = tid; t < 56 * 7; t += 256) {
    int r = t / 7, ch = t - r * 7;
    u32x4 q = *(const u32x4*)(hp + r * Wd + ch * 8);
    float* dst = &sp[(r + 1) * 60 + 1 + ch * 8];
    u32 ua[4] = {q.x, q.y, q.z, q.w};
    #pragma unroll
    for (int j = 0; j < 4; ++j) {
      dst[2 * j]     = bflo(ua[j]);
      dst[2 * j + 1] = bfhi(ua[j]);
    }
  }
  float wv[9];
  #pragma unroll
  for (int t = 0; t < 9; ++t) wv[t] = wdw[c * 9 + t];
  float sc = g2[c] * rsqrtf(v2[c] + EPS);
  float sh = b2[c] - m2[c] * sc;
  __syncthreads();

  u16* dp = d + (size_t)(b * HID + c) * HW;
  float lsum = 0.f;
  for (int g = tid; g < 784; g += 256) {
    int row = g / 14, gx = (g - row * 14) * 4;
    float v[3][6];
    #pragma unroll
    for (int r = 0; r < 3; ++r) {
      const float* pr = &sp[(row + r) * 60 + gx];
      f32x4 a = *(const f32x4*)pr;
      v[r][0] = a.x; v[r][1] = a.y; v[r][2] = a.z; v[r][3] = a.w;
      v[r][4] = pr[4]; v[r][5] = pr[5];
    }
    float o[4];
    #pragma unroll
    for (int j = 0; j < 4; ++j) {
      float s = 0.f;
      #pragma unroll
      for (int r = 0; r < 3; ++r)
        #pragma unroll
        for (int dx = 0; dx < 3; ++dx)
          s += v[r][j + dx] * wv[r * 3 + dx];
      o[j] = fsilu(s * sc + sh);
      lsum += o[j];
    }
    u32x2 pk;
    pk.x = (u32)f2b(o[0]) | ((u32)f2b(o[1]) << 16);
    pk.y = (u32)f2b(o[2]) | ((u32)f2b(o[3]) << 16);
    *(u32x2*)&dp[row * 56 + gx] = pk;
  }
  #pragma unroll
  for (int off = 32; off > 0; off >>= 1) lsum += __shfl_down(lsum, off);
  if ((tid & 63) == 0) red[tid >> 6] = lsum;
  __syncthreads();
  if (tid == 0)
    mean[b * HID + c] = (red[0] + red[1] + red[2] + red[3]) * (1.f / 3136.f);
}

// ---------------------------------------------------------------------------
// K3: SE + A'-fold fused. grid bc, block 256.
// ---------------------------------------------------------------------------
__global__ __launch_bounds__(256) void k_se_a(
    const float* __restrict__ mean, const float* __restrict__ w1,
    const float* __restrict__ w2, const float* __restrict__ wpw,
    const float* __restrict__ sc3, u16* __restrict__ afold)
{
  __shared__ float sm[HID];
  __shared__ float ps[16 * 17];
  __shared__ float s1[16];
  __shared__ float sf[HID];
  const int b = blockIdx.x, tid = threadIdx.x;
  for (int c = tid; c < HID; c += 256) sm[c] = mean[b * HID + c];
  __syncthreads();
  int r = tid >> 4, j = tid & 15;
  float p = 0.f;
  for (int c = j; c < HID; c += 16) p += sm[c] * w1[r * HID + c];
  ps[r * 17 + j] = p;
  __syncthreads();
  if (tid < 16) {
    float s = 0.f;
    #pragma unroll
    for (int q = 0; q < 16; ++q) s += ps[tid * 17 + q];
    s1[tid] = fsilu(s);
  }
  __syncthreads();
  for (int c = tid; c < HID; c += 256) {
    float s = 0.f;
    #pragma unroll
    for (int q = 0; q < 16; ++q) s += s1[q] * w2[c * 16 + q];
    sf[c] = 1.f / (1.f + __expf(-s));
  }
  __syncthreads();
  for (int i = tid; i < 6144; i += 256) {    // f32x4 chunks of 64x384
    int e = i * 4, co = e / 384, k = e - co * 384;
    f32x4 wv = *(const f32x4*)&wpw[e];
    float s3 = sc3[co];
    u32x2 pk;
    pk.x = (u32)f2b(wv.x * sf[k] * s3)     | ((u32)f2b(wv.y * sf[k+1] * s3) << 16);
    pk.y = (u32)f2b(wv.z * sf[k+2] * s3)   | ((u32)f2b(wv.w * sf[k+3] * s3) << 16);
    *(u32x2*)&afold[(size_t)b * 24576 + e] = pk;
  }
}

// ---------------------------------------------------------------------------
// K4: pointwise MFMA GEMM. grid (25 px-tiles of 128, bc b), 256 thr.
// ---------------------------------------------------------------------------
constexpr int PWP = 392;

__global__ __launch_bounds__(256, 2) void k_pw_mfma(
    const u16* __restrict__ d, const u16* __restrict__ afold,
    const float* __restrict__ sh3,
    const float* __restrict__ x, float* __restrict__ out, int b0)
{
  __shared__ u16 sAw[64 * PWP];     // 50,176 B
  __shared__ u32 dt32[128 * 16];    // 8,192 B
  const int tid = threadIdx.x;
  const int b = blockIdx.y, gb = b0 + b;
  const int p0 = blockIdx.x * 128;
  const int wave = tid >> 6, ln = tid & 63;
  const int lane15 = ln & 15, quad = ln >> 4;

  // stage A' (pure b128 copies): 24576 elems = 3072 x 8
  {
    const u16* ab = afold + (size_t)b * 24576;
    #pragma unroll
    for (int i = tid; i < 3072; i += 256) {
      int e = i * 8, co = e / 384, k = e - co * 384;
      *(u32x4*)&sAw[co * PWP + k] = *(const u32x4*)&ab[e];
    }
  }

  f32x4 acc[4][2];
  #pragma unroll
  for (int ms = 0; ms < 4; ++ms)
    #pragma unroll
    for (int ns = 0; ns < 2; ++ns) acc[ms][ns] = (f32x4){0.f, 0.f, 0.f, 0.f};

  const int cpair = tid >> 4;
  const int pxo = (tid & 15) * 8;

  for (int ks = 0; ks < 12; ++ks) {
    const int k0 = ks * 32;
    __syncthreads();
    {
      u32x4 r0 = {0,0,0,0}, r1 = {0,0,0,0};
      if (p0 + pxo + 8 <= HW) {
        int c = k0 + 2 * cpair;
        const u16* dpp = d + (size_t)(b * HID + c) * HW + p0 + pxo;
        r0 = *(const u32x4*)dpp;
        r1 = *(const u32x4*)(dpp + HW);
      }
      u32* w0 = &dt32[pxo * 16 + cpair];
      w0[0 * 16] = (r0.x & 0xffffu) | (r1.x << 16);
      w0[1 * 16] = (r0.x >> 16)     | (r1.x & 0xffff0000u);
      w0[2 * 16] = (r0.y & 0xffffu) | (r1.y << 16);
      w0[3 * 16] = (r0.y >> 16)     | (r1.y & 0xffff0000u);
      w0[4 * 16] = (r0.z & 0xffffu) | (r1.z << 16);
      w0[5 * 16] = (r0.z >> 16)     | (r1.z & 0xffff0000u);
      w0[6 * 16] = (r0.w & 0xffffu) | (r1.w << 16);
      w0[7 * 16] = (r0.w >> 16)     | (r1.w & 0xffff0000u);
    }
    __syncthreads();
    s16x8 af[4], bf[2];
    #pragma unroll
    for (int ms = 0; ms < 4; ++ms) {
      int ocl = ms * 16 + lane15;
      af[ms] = *(const s16x8*)&sAw[ocl * PWP + k0 + quad * 8];
    }
    #pragma unroll
    for (int ns = 0; ns < 2; ++ns) {
      int px = wave * 32 + ns * 16 + lane15;
      bf[ns] = *(const s16x8*)((const u16*)dt32 + px * 32 + quad * 8);
    }
    #pragma unroll
    for (int ms = 0; ms < 4; ++ms)
      #pragma unroll
      for (int ns = 0; ns < 2; ++ns)
        acc[ms][ns] = __builtin_amdgcn_mfma_f32_16x16x32_bf16(
            af[ms], bf[ns], acc[ms][ns], 0, 0, 0);
  }

  #pragma unroll
  for (int ns = 0; ns < 2; ++ns) {
    int p = p0 + wave * 32 + ns * 16 + lane15;
    if (p < HW) {
      #pragma unroll
      for (int ms = 0; ms < 4; ++ms) {
        int co0 = ms * 16 + quad * 4;
        float av[4] = {acc[ms][ns].x, acc[ms][ns].y, acc[ms][ns].z, acc[ms][ns].w};
        #pragma unroll
        for (int r = 0; r < 4; ++r) {
          size_t idx = (size_t)(gb * CO + co0 + r) * HW + p;
          out[idx] = av[r] + sh3[co0 + r] + x[idx];
        }
      }
    }
  }
}

// ---------------------------------------------------------------------------
extern "C" void kernel_launch(void* const* d_in, const int* in_sizes, int n_in,
                              void* d_out, int out_size, void* d_ws, size_t ws_size,
                              hipStream_t stream)
{
  (void)in_sizes; (void)n_in; (void)out_size;
  const float* x     = (const float*)d_in[0];
  const float* w_exp = (const float*)d_in[1];
  const float* g1 = (const float*)d_in[2];
  const float* b1 = (const float*)d_in[3];
  const float* m1 = (const float*)d_in[4];
  const float* v1 = (const float*)d_in[5];
  const float* w_dw = (const float*)d_in[6];
  const float* g2 = (const float*)d_in[7];
  const float* b2 = (const float*)d_in[8];
  const float* m2 = (const float*)d_in[9];
  const float* v2 = (const float*)d_in[10];
  const float* w_se1 = (const float*)d_in[11];
  const float* w_se2 = (const float*)d_in[12];
  const float* w_pw  = (const float*)d_in[13];
  const float* g3 = (const float*)d_in[14];
  const float* b3 = (const float*)d_in[15];
  const float* m3 = (const float*)d_in[16];
  const float* v3 = (const float*)d_in[17];

  const size_t perB = (size_t)XBATCH * 2 + (size_t)HID * HW * 2 * 2
                    + 24576 * 2 + HID * 4;
  const size_t fixed = 221184 * 2 + HID * 8 + CO * 8;
  int bc = Bn;
  while (bc > 1 && fixed + (size_t)bc * perB > ws_size) bc >>= 1;

  u16* wt = (u16*)d_ws;
  float* sc1 = (float*)(wt + 221184);
  float* sh1 = sc1 + HID;
  float* sc3 = sh1 + HID;
  float* sh3 = sc3 + CO;
  u16* xt = (u16*)(sh3 + CO);
  u16* h  = xt + (size_t)bc * XBATCH;
  u16* dd = h + (size_t)bc * HID * HW;
  u16* afold = dd + (size_t)bc * HID * HW;
  float* mean = (float*)(afold + (size_t)bc * 24576);

  k_prep_w<<<864, 256, 0, stream>>>(w_exp, wt);
  k_prep_bn<<<1, 384, 0, stream>>>(g1, b1, m1, v1, g3, b3, m3, v3,
                                   sc1, sh1, sc3, sh3);

  for (int b0 = 0; b0 < Bn; b0 += bc) {
    k_prep_x<<<dim3(58, bc), 256, 0, stream>>>(x, xt, b0);
    k_expand_mfma<<<dim3(3, 14, bc), 256, 0, stream>>>(xt, wt, sc1, sh1, h);
    k_dw<<<dim3(HID, bc), 256, 0, stream>>>(h, w_dw, g2, b2, m2, v2, dd, mean);
    k_se_a<<<bc, 256, 0, stream>>>(mean, w_se1, w_se2, w_pw, sc3, afold);
    k_pw_mfma<<<dim3(25, bc), 256, 0, stream>>>(dd, afold, sh3,
                                                x, (float*)d_out, b0);
  }
}